// Round 4
// baseline (99.171 us; speedup 1.0000x reference)
//
#include <hip/hip_runtime.h>
#include <hip/hip_bf16.h>

typedef __attribute__((ext_vector_type(8))) short short8;   // 8 x bf16 (4 VGPR)
typedef __attribute__((ext_vector_type(4))) float f32x4;
typedef __attribute__((ext_vector_type(4))) int   i32x4;

#define KD 4096
#define ND 16384
#define MD 128

// round-to-nearest-even f32 -> bf16 bits
__device__ __forceinline__ ushort f2bf_rn(float f) {
    unsigned u = __float_as_uint(f);
    u += 0x7FFFu + ((u >> 16) & 1u);
    return (ushort)(u >> 16);
}

// exact for |v| <= 127: int -> f32 -> truncate to bf16 (small ints have zero low mantissa bits)
__device__ __forceinline__ ushort i2bf(int v) {
    return (ushort)(__float_as_uint((float)v) >> 16);
}

// Pack x[128][4096] f32 into bf16 MFMA A-fragment order (verified r1/r3):
// xp[kb][mt][lane][j] = x[16*mt + (lane&15)][32*kb + 8*(lane>>4) + j]   (1 MiB)
__global__ __launch_bounds__(256) void pack_x_kernel(const float* __restrict__ x,
                                                     ushort* __restrict__ xp) {
    int tid  = blockIdx.x * 256 + threadIdx.x;   // 0..65535
    int lane = tid & 63;
    int mt   = (tid >> 6) & 7;
    int kb   = tid >> 9;                          // 0..127
    int m = (mt << 4) + (lane & 15);
    int k = (kb << 5) + ((lane >> 4) << 3);
    const f32x4* src = reinterpret_cast<const f32x4*>(x + (size_t)m * KD + k);
    f32x4 a = src[0];
    f32x4 b = src[1];
    short8 v;
    v[0] = (short)f2bf_rn(a[0]); v[1] = (short)f2bf_rn(a[1]);
    v[2] = (short)f2bf_rn(a[2]); v[3] = (short)f2bf_rn(a[3]);
    v[4] = (short)f2bf_rn(b[0]); v[5] = (short)f2bf_rn(b[1]);
    v[6] = (short)f2bf_rn(b[2]); v[7] = (short)f2bf_rn(b[3]);
    *reinterpret_cast<short8*>(xp + (size_t)tid * 8) = v;
}

#define GLOAD_LDS16(g, l)                                                        \
    __builtin_amdgcn_global_load_lds((const __attribute__((address_space(1))) void*)(g), \
                                     (__attribute__((address_space(3))) void*)(l), 16, 0, 0)

// counted-vmcnt phase boundary: stage(t) landed, my prior ds_reads drained, then barrier
#define WAITB(n) do {                                                            \
        asm volatile("s_waitcnt vmcnt(" #n ") lgkmcnt(0)" ::: "memory");         \
        __builtin_amdgcn_s_barrier();                                            \
    } while (0)

// Block: 64 output cols x 64 output rows (m-half) x full K=4096.
// Grid 512 = 256 n-groups x 2 m-halves; pair (nb, nb+256) shares W cols on the same XCD.
// LDS: A 3x8KiB + W 3x16KiB = 72 KiB -> 2 blocks/CU.
// Depth-3 pipeline, all-VMEM = global_load_lds -> counted vmcnt is sound:
//   phase t: wait vmcnt(6) [stage(t) landed, stage(t+1) in flight]; barrier;
//            STAGE(t+2); COMPUTE(t).
__global__ __launch_bounds__(256, 2) void gemm_kernel(const int* __restrict__ wgt,
                                                      const ushort* __restrict__ xp,
                                                      const float* __restrict__ scales,
                                                      const float* __restrict__ bias,
                                                      float* __restrict__ out) {
    __shared__ __align__(16) char lds[73728];   // A: 3x8K at [0,24K)  W: 3x16K at [24K,72K)

    const int tid  = threadIdx.x;
    const int lane = tid & 63;
    const int w    = tid >> 6;          // wave 0..3 -> col group [16w,16w+16)
    const int nb   = blockIdx.x & 255;  // n-group
    const int h    = blockIdx.x >> 8;   // m-half
    const int n0   = nb << 6;
    const int cl   = lane & 15;
    const int cq   = lane >> 4;         // k-quarter 0..3

    // ---- A staging source (per-lane, advances 16 KiB per chunk) ----
    const char* asrc = (const char*)xp + (h << 12) + (w << 10) + (lane << 4);

    // ---- W staging sources: issue _i covers cols c = 16w + 4_i + cq ----
    // pre-swizzled source so the LINEAR gload_lds dest realizes layout
    // off(c,k) = c*256 + ((4k) ^ ((c&7)<<4))   [verified r3]
    const int* wsrc0;
    const int* wsrc1;
    const int* wsrc2;
    const int* wsrc3;
    {
        int c0 = (w << 4) + 0  + cq;
        int c1 = (w << 4) + 4  + cq;
        int c2 = (w << 4) + 8  + cq;
        int c3 = (w << 4) + 12 + cq;
        wsrc0 = wgt + (size_t)(n0 + c0) * KD + ((cl ^ (c0 & 7)) << 2);
        wsrc1 = wgt + (size_t)(n0 + c1) * KD + ((cl ^ (c1 & 7)) << 2);
        wsrc2 = wgt + (size_t)(n0 + c2) * KD + ((cl ^ (c2 & 7)) << 2);
        wsrc3 = wgt + (size_t)(n0 + c3) * KD + ((cl ^ (c3 & 7)) << 2);
    }

    f32x4 acc[4];
#pragma unroll
    for (int i = 0; i < 4; ++i) acc[i] = (f32x4){0.f, 0.f, 0.f, 0.f};

    // LDS dest bases (wave-uniform; HW adds lane*16)
    char* dA = lds + (w << 10);                       // + b*8192 + j*4096
    char* dW = lds + 24576 + (w << 12);               // + b*16384 + _i*1024

#define STAGE(t, b) do {                                                        \
        const char* _as = asrc + (size_t)(t) * 16384;                           \
        GLOAD_LDS16(_as,        dA + (b) * 8192);                               \
        GLOAD_LDS16(_as + 8192, dA + (b) * 8192 + 4096);                        \
        const int _k0 = (t) * 64;                                               \
        GLOAD_LDS16(wsrc0 + _k0, dW + (b) * 16384);                             \
        GLOAD_LDS16(wsrc1 + _k0, dW + (b) * 16384 + 1024);                      \
        GLOAD_LDS16(wsrc2 + _k0, dW + (b) * 16384 + 2048);                      \
        GLOAD_LDS16(wsrc3 + _k0, dW + (b) * 16384 + 3072);                      \
    } while (0)

    // compute-side read bases
    const char* rA = lds + (lane << 4);                         // + b*8192 + kbl*4096 + m*1024
    const char* rW = lds + 24576 + (((w << 4) + cl) << 8);      // + b*16384 + inner
    const int sw   = (cl & 7) << 4;
    const int q32  = cq << 5;

#define COMPUTE(b) do {                                                         \
        _Pragma("unroll")                                                       \
        for (int _kbl = 0; _kbl < 2; ++_kbl) {                                  \
            int _ib = ((_kbl << 7) + q32) ^ sw;                                 \
            i32x4 _lo = *reinterpret_cast<const i32x4*>(rW + (b) * 16384 + _ib);        \
            i32x4 _hi = *reinterpret_cast<const i32x4*>(rW + (b) * 16384 + (_ib ^ 16)); \
            short8 _bf;                                                         \
            _bf[0] = (short)i2bf(_lo[0]); _bf[1] = (short)i2bf(_lo[1]);         \
            _bf[2] = (short)i2bf(_lo[2]); _bf[3] = (short)i2bf(_lo[3]);         \
            _bf[4] = (short)i2bf(_hi[0]); _bf[5] = (short)i2bf(_hi[1]);         \
            _bf[6] = (short)i2bf(_hi[2]); _bf[7] = (short)i2bf(_hi[3]);         \
            const char* _ab = rA + (b) * 8192 + _kbl * 4096;                    \
            _Pragma("unroll")                                                   \
            for (int _m = 0; _m < 4; ++_m) {                                    \
                short8 _af = *reinterpret_cast<const short8*>(_ab + _m * 1024); \
                acc[_m] = __builtin_amdgcn_mfma_f32_16x16x32_bf16(_af, _bf, acc[_m], 0, 0, 0); \
            }                                                                   \
        }                                                                       \
    } while (0)

    // ---- main loop: 64 chunks of K=64, buffer = chunk % 3 ----
    STAGE(0, 0);
    STAGE(1, 1);

#pragma unroll 1
    for (int i = 0; i < 20; ++i) {
        const int t = i * 3;
        WAITB(6); STAGE(t + 2, 2); COMPUTE(0);    // chunk t   (b0)
        WAITB(6); STAGE(t + 3, 0); COMPUTE(1);    // chunk t+1 (b1)
        WAITB(6); STAGE(t + 4, 1); COMPUTE(2);    // chunk t+2 (b2)
    }
    // chunks 60..63; staged so far: 0..61
    WAITB(6); STAGE(62, 2); COMPUTE(0);           // chunk 60
    WAITB(6); STAGE(63, 0); COMPUTE(1);           // chunk 61
    WAITB(6);                COMPUTE(2);          // chunk 62 (only stage63 outstanding)
    WAITB(0);                COMPUTE(0);          // chunk 63 (drained)

    // ---- epilogue: scale + bias, direct store (block owns its 64x64 tile) ----
    const int ncol = n0 + (w << 4) + cl;
    const float s  = scales[ncol] * (1.0f / 127.0f);
    const float bv = bias[ncol];
    const int rb = cq << 2;
#pragma unroll
    for (int m = 0; m < 4; ++m) {
#pragma unroll
        for (int r = 0; r < 4; ++r) {
            int mg = (h << 6) + (m << 4) + rb + r;
            out[(size_t)mg * ND + ncol] = acc[m][r] * s + bv;
        }
    }
#undef STAGE
#undef COMPUTE
}

extern "C" void kernel_launch(void* const* d_in, const int* in_sizes, int n_in,
                              void* d_out, int out_size, void* d_ws, size_t ws_size,
                              hipStream_t stream) {
    const float* x      = (const float*)d_in[0];
    const int*   wgt    = (const int*)d_in[1];     // int8 promoted to int32 by harness
    const float* scales = (const float*)d_in[2];
    const float* bias   = (const float*)d_in[3];
    float* out = (float*)d_out;
    ushort* xp = (ushort*)d_ws;                    // 1 MiB bf16 packed x

    pack_x_kernel<<<MD * KD / (8 * 256), 256, 0, stream>>>(x, xp);
    gemm_kernel<<<512, 256, 0, stream>>>(wgt, xp, scales, bias, out);
}

// Round 5
// 87.478 us; speedup vs baseline: 1.1337x; 1.1337x over previous
//
#include <hip/hip_runtime.h>
#include <hip/hip_bf16.h>

typedef __attribute__((ext_vector_type(8))) short short8;   // 8 x bf16 (4 VGPR)
typedef __attribute__((ext_vector_type(4))) float f32x4;
typedef __attribute__((ext_vector_type(4))) int   i32x4;

#define KD 4096
#define ND 16384
#define MD 128

// round-to-nearest-even f32 -> bf16 bits
__device__ __forceinline__ ushort f2bf_rn(float f) {
    unsigned u = __float_as_uint(f);
    u += 0x7FFFu + ((u >> 16) & 1u);
    return (ushort)(u >> 16);
}

// exact for |v| <= 127: int -> f32 -> truncate to bf16 (small ints have zero low mantissa bits)
__device__ __forceinline__ ushort i2bf(int v) {
    return (ushort)(__float_as_uint((float)v) >> 16);
}

// Pack x[128][4096] f32 into bf16 MFMA A-fragment order (verified r1/r3):
// xp[kb][mt][lane][j] = x[16*mt + (lane&15)][32*kb + 8*(lane>>4) + j]   (1 MiB)
__global__ __launch_bounds__(256) void pack_x_kernel(const float* __restrict__ x,
                                                     ushort* __restrict__ xp) {
    int tid  = blockIdx.x * 256 + threadIdx.x;   // 0..65535
    int lane = tid & 63;
    int mt   = (tid >> 6) & 7;
    int kb   = tid >> 9;                          // 0..127
    int m = (mt << 4) + (lane & 15);
    int k = (kb << 5) + ((lane >> 4) << 3);
    const f32x4* src = reinterpret_cast<const f32x4*>(x + (size_t)m * KD + k);
    f32x4 a = src[0];
    f32x4 b = src[1];
    short8 v;
    v[0] = (short)f2bf_rn(a[0]); v[1] = (short)f2bf_rn(a[1]);
    v[2] = (short)f2bf_rn(a[2]); v[3] = (short)f2bf_rn(a[3]);
    v[4] = (short)f2bf_rn(b[0]); v[5] = (short)f2bf_rn(b[1]);
    v[6] = (short)f2bf_rn(b[2]); v[7] = (short)f2bf_rn(b[3]);
    *reinterpret_cast<short8*>(xp + (size_t)tid * 8) = v;
}

// lgkm-only phase barrier: my ds_writes (and ds_reads of the buffer being
// recycled) are complete; does NOT touch vmcnt -> in-flight global loads
// survive the barrier. Cross-wave data flows only through ds_write, so this
// is sound regardless of compiler waitcnt placement.
#define BARRIER() do {                                                          \
        asm volatile("s_waitcnt lgkmcnt(0)" ::: "memory");                      \
        __builtin_amdgcn_s_barrier();                                           \
    } while (0)

// Block: 64 output cols x 64 output rows (m-half) x full K=4096.
// Grid 512 = 256 n-groups x 2 m-halves; pair (nb, nb+256) shares W cols on the same XCD.
// LDS map identical to r3: A dbuf 2x8KiB [0,16K), W dbuf 2x16KiB [16K,48K).
// Pipeline: loads for chunk t+2 issued (global->reg) at phase t; ds_write of
// chunk t+1's regs at phase t; compute(t). Register deps give the compiler
// exact vmcnt placement; no vmcnt(0) drain anywhere in the loop.
__global__ __launch_bounds__(256, 2) void gemm_kernel(const int* __restrict__ wgt,
                                                      const ushort* __restrict__ xp,
                                                      const float* __restrict__ scales,
                                                      const float* __restrict__ bias,
                                                      float* __restrict__ out) {
    __shared__ __align__(16) char lds[49152];

    const int tid  = threadIdx.x;
    const int lane = tid & 63;
    const int w    = tid >> 6;          // wave 0..3 -> col group [16w,16w+16)
    const int nb   = blockIdx.x & 255;  // n-group
    const int h    = blockIdx.x >> 8;   // m-half
    const int n0   = nb << 6;
    const int cl   = lane & 15;
    const int cq   = lane >> 4;         // k-quarter 0..3

    // ---- global sources (identical to r3) ----
    const char* asrc = (const char*)xp + (h << 12) + (w << 10) + (lane << 4);
    const int* wsrc0;
    const int* wsrc1;
    const int* wsrc2;
    const int* wsrc3;
    {
        int c0 = (w << 4) + 0  + cq;
        int c1 = (w << 4) + 4  + cq;
        int c2 = (w << 4) + 8  + cq;
        int c3 = (w << 4) + 12 + cq;
        wsrc0 = wgt + (size_t)(n0 + c0) * KD + ((cl ^ (c0 & 7)) << 2);
        wsrc1 = wgt + (size_t)(n0 + c1) * KD + ((cl ^ (c1 & 7)) << 2);
        wsrc2 = wgt + (size_t)(n0 + c2) * KD + ((cl ^ (c2 & 7)) << 2);
        wsrc3 = wgt + (size_t)(n0 + c3) * KD + ((cl ^ (c3 & 7)) << 2);
    }

    // ---- LDS write addresses (replicate gload_lds's base + lane*16 layout) ----
    char* wAp = lds + (w << 10) + (lane << 4);            // + b*8192 + j*4096
    char* wWp = lds + 16384 + (w << 12) + (lane << 4);    // + b*16384 + i*1024

    f32x4 acc[4];
#pragma unroll
    for (int i = 0; i < 4; ++i) acc[i] = (f32x4){0.f, 0.f, 0.f, 0.f};

    // two staging register sets (stage t lives in set t&1)
    i32x4 SAa0, SAa1, SAw0, SAw1, SAw2, SAw3;
    i32x4 SBa0, SBa1, SBw0, SBw1, SBw2, SBw3;

#define LOADSET(S, t) do {                                                      \
        const char* _as = asrc + (size_t)(t) * 16384;                           \
        S##a0 = *reinterpret_cast<const i32x4*>(_as);                           \
        S##a1 = *reinterpret_cast<const i32x4*>(_as + 8192);                    \
        const int _k0 = (t) * 64;                                               \
        S##w0 = *reinterpret_cast<const i32x4*>(wsrc0 + _k0);                   \
        S##w1 = *reinterpret_cast<const i32x4*>(wsrc1 + _k0);                   \
        S##w2 = *reinterpret_cast<const i32x4*>(wsrc2 + _k0);                   \
        S##w3 = *reinterpret_cast<const i32x4*>(wsrc3 + _k0);                   \
    } while (0)

#define WRITESET(S, b) do {                                                     \
        *reinterpret_cast<i32x4*>(wAp + (b) * 8192)         = S##a0;            \
        *reinterpret_cast<i32x4*>(wAp + (b) * 8192 + 4096)  = S##a1;            \
        *reinterpret_cast<i32x4*>(wWp + (b) * 16384)        = S##w0;            \
        *reinterpret_cast<i32x4*>(wWp + (b) * 16384 + 1024) = S##w1;            \
        *reinterpret_cast<i32x4*>(wWp + (b) * 16384 + 2048) = S##w2;            \
        *reinterpret_cast<i32x4*>(wWp + (b) * 16384 + 3072) = S##w3;            \
    } while (0)

    // compute-side read bases (identical to r3)
    const char* rA = lds + (lane << 4);                         // + b*8192 + kbl*4096 + m*1024
    const char* rW = lds + 16384 + (((w << 4) + cl) << 8);      // + b*16384 + inner
    const int sw   = (cl & 7) << 4;
    const int q32  = cq << 5;

#define COMPUTE(b) do {                                                         \
        _Pragma("unroll")                                                       \
        for (int _kbl = 0; _kbl < 2; ++_kbl) {                                  \
            int _ib = ((_kbl << 7) + q32) ^ sw;                                 \
            i32x4 _lo = *reinterpret_cast<const i32x4*>(rW + (b) * 16384 + _ib);        \
            i32x4 _hi = *reinterpret_cast<const i32x4*>(rW + (b) * 16384 + (_ib ^ 16)); \
            short8 _bf;                                                         \
            _bf[0] = (short)i2bf(_lo[0]); _bf[1] = (short)i2bf(_lo[1]);         \
            _bf[2] = (short)i2bf(_lo[2]); _bf[3] = (short)i2bf(_lo[3]);         \
            _bf[4] = (short)i2bf(_hi[0]); _bf[5] = (short)i2bf(_hi[1]);         \
            _bf[6] = (short)i2bf(_hi[2]); _bf[7] = (short)i2bf(_hi[3]);         \
            const char* _ab = rA + (b) * 8192 + _kbl * 4096;                    \
            _Pragma("unroll")                                                   \
            for (int _m = 0; _m < 4; ++_m) {                                    \
                short8 _af = *reinterpret_cast<const short8*>(_ab + _m * 1024); \
                acc[_m] = __builtin_amdgcn_mfma_f32_16x16x32_bf16(_af, _bf, acc[_m], 0, 0, 0); \
            }                                                                   \
        }                                                                       \
    } while (0)

    // ---- prologue ----
    LOADSET(SA, 0);                 // stage 0 -> regs
    LOADSET(SB, 1);                 // stage 1 -> regs
    WRITESET(SA, 0);                // compiler waits vmcnt(6): SA landed, SB in flight
    BARRIER();

    // ---- main loop: chunks 0..61 in pairs ----
#pragma unroll 1
    for (int t = 0; t < 62; t += 2) {
        LOADSET(SA, t + 2);         // issue early (2 phases ahead of its ds_write)
        COMPUTE(0);                 // chunk t   (buf0)
        WRITESET(SB, 1);            // stage t+1 -> buf1 (vmcnt(6): SB landed)
        BARRIER();

        LOADSET(SB, t + 3);
        COMPUTE(1);                 // chunk t+1 (buf1)
        WRITESET(SA, 0);            // stage t+2 -> buf0
        BARRIER();
    }

    // ---- tail: chunks 62, 63 (SB holds stage 63) ----
    COMPUTE(0);                     // chunk 62
    WRITESET(SB, 1);                // stage 63 -> buf1
    BARRIER();
    COMPUTE(1);                     // chunk 63

    // ---- epilogue: scale + bias, direct store (block owns its 64x64 tile) ----
    const int ncol = n0 + (w << 4) + cl;
    const float s  = scales[ncol] * (1.0f / 127.0f);
    const float bv = bias[ncol];
    const int rb = cq << 2;
#pragma unroll
    for (int m = 0; m < 4; ++m) {
#pragma unroll
        for (int r = 0; r < 4; ++r) {
            int mg = (h << 6) + (m << 4) + rb + r;
            out[(size_t)mg * ND + ncol] = acc[m][r] * s + bv;
        }
    }
#undef LOADSET
#undef WRITESET
#undef COMPUTE
}

extern "C" void kernel_launch(void* const* d_in, const int* in_sizes, int n_in,
                              void* d_out, int out_size, void* d_ws, size_t ws_size,
                              hipStream_t stream) {
    const float* x      = (const float*)d_in[0];
    const int*   wgt    = (const int*)d_in[1];     // int8 promoted to int32 by harness
    const float* scales = (const float*)d_in[2];
    const float* bias   = (const float*)d_in[3];
    float* out = (float*)d_out;
    ushort* xp = (ushort*)d_ws;                    // 1 MiB bf16 packed x

    pack_x_kernel<<<MD * KD / (8 * 256), 256, 0, stream>>>(x, xp);
    gemm_kernel<<<512, 256, 0, stream>>>(wgt, xp, scales, bias, out);
}

// Round 6
// 79.275 us; speedup vs baseline: 1.2510x; 1.1035x over previous
//
#include <hip/hip_runtime.h>
#include <hip/hip_bf16.h>

typedef __attribute__((ext_vector_type(8))) short short8;   // 8 x bf16 (4 VGPR)
typedef __attribute__((ext_vector_type(4))) float f32x4;
typedef __attribute__((ext_vector_type(4))) int   i32x4;

#define KD 4096
#define ND 16384
#define MD 128

// round-to-nearest-even f32 -> bf16 bits
__device__ __forceinline__ ushort f2bf_rn(float f) {
    unsigned u = __float_as_uint(f);
    u += 0x7FFFu + ((u >> 16) & 1u);
    return (ushort)(u >> 16);
}

// exact for |v| <= 127: int -> f32 -> truncate to bf16 (small ints have zero low mantissa bits)
__device__ __forceinline__ ushort i2bf(int v) {
    return (ushort)(__float_as_uint((float)v) >> 16);
}

// Pack x[128][4096] f32 into bf16 MFMA A-fragment order (verified r1/r3):
// xp[kb][mt][lane][j] = x[16*mt + (lane&15)][32*kb + 8*(lane>>4) + j]   (1 MiB)
__global__ __launch_bounds__(256) void pack_x_kernel(const float* __restrict__ x,
                                                     ushort* __restrict__ xp) {
    int tid  = blockIdx.x * 256 + threadIdx.x;   // 0..65535
    int lane = tid & 63;
    int mt   = (tid >> 6) & 7;
    int kb   = tid >> 9;                          // 0..127
    int m = (mt << 4) + (lane & 15);
    int k = (kb << 5) + ((lane >> 4) << 3);
    const f32x4* src = reinterpret_cast<const f32x4*>(x + (size_t)m * KD + k);
    f32x4 a = src[0];
    f32x4 b = src[1];
    short8 v;
    v[0] = (short)f2bf_rn(a[0]); v[1] = (short)f2bf_rn(a[1]);
    v[2] = (short)f2bf_rn(a[2]); v[3] = (short)f2bf_rn(a[3]);
    v[4] = (short)f2bf_rn(b[0]); v[5] = (short)f2bf_rn(b[1]);
    v[6] = (short)f2bf_rn(b[2]); v[7] = (short)f2bf_rn(b[3]);
    *reinterpret_cast<short8*>(xp + (size_t)tid * 8) = v;
}

#define GLOAD_LDS16(g, l)                                                        \
    __builtin_amdgcn_global_load_lds((const __attribute__((address_space(1))) void*)(g), \
                                     (__attribute__((address_space(3))) void*)(l), 16, 0, 0)

// Block: 32 output cols x 64 output rows (m-half) x full K=4096. 128 threads (2 waves).
// Grid 1024 = 512 n-groups x 2 m-halves -> 4 blocks/CU (LDS 4x32KiB=128KiB), so four
// INDEPENDENT 2-phase pipelines interleave per CU: one block's syncthreads-drain
// overlaps the other three blocks' HBM deliveries (r3 had only 2 -> ~70% eff).
// Pair (nb, nb+512) shares W cols on the same XCD (512%8==0) -> L2 dedup (verified r3).
// Structure is byte-for-byte r3's verified 2-phase template otherwise.
__global__ __launch_bounds__(128, 2) void gemm_kernel(const int* __restrict__ wgt,
                                                      const ushort* __restrict__ xp,
                                                      const float* __restrict__ scales,
                                                      const float* __restrict__ bias,
                                                      float* __restrict__ out) {
    __shared__ __align__(16) char lds[32768];   // A: 2x8K at [0,16K)  W: 2x8K at [16K,32K)

    const int tid  = threadIdx.x;
    const int lane = tid & 63;
    const int w    = tid >> 6;          // wave 0..1 -> col group [16w,16w+16)
    const int nb   = blockIdx.x & 511;  // n-group (32 cols)
    const int h    = blockIdx.x >> 9;   // m-half
    const int n0   = nb << 5;
    const int cl   = lane & 15;
    const int cq   = lane >> 4;         // k-quarter 0..3

    // ---- A staging source: chunk t covers kb = 2t + j; wave w stages slot j=w ----
    // src byte = (2t+w)*8192 + h*4096 + q*1024 + lane*16   (q = m-tile 0..3)
    const char* asrc = (const char*)xp + (h << 12) + (lane << 4);

    // ---- W staging sources: wave-issue i covers cols c = 16w + 4i + cq ----
    // pre-swizzled source so the LINEAR gload_lds dest realizes layout
    // off(c,k16) = c*256 + ((k16*16) ^ ((c&7)<<4))   [verified r3]
    const int* wsrc0;
    const int* wsrc1;
    const int* wsrc2;
    const int* wsrc3;
    {
        int c0 = (w << 4) + 0  + cq;
        int c1 = (w << 4) + 4  + cq;
        int c2 = (w << 4) + 8  + cq;
        int c3 = (w << 4) + 12 + cq;
        wsrc0 = wgt + (size_t)(n0 + c0) * KD + ((cl ^ (c0 & 7)) << 2);
        wsrc1 = wgt + (size_t)(n0 + c1) * KD + ((cl ^ (c1 & 7)) << 2);
        wsrc2 = wgt + (size_t)(n0 + c2) * KD + ((cl ^ (c2 & 7)) << 2);
        wsrc3 = wgt + (size_t)(n0 + c3) * KD + ((cl ^ (c3 & 7)) << 2);
    }

    f32x4 acc[4];
#pragma unroll
    for (int i = 0; i < 4; ++i) acc[i] = (f32x4){0.f, 0.f, 0.f, 0.f};

    // LDS dest bases (wave-uniform; HW adds lane*16)
    char* dA = lds + (w << 12);               // + b*8192 + q*1024
    char* dW = lds + 16384 + (w << 12);       // + b*8192 + i*1024

#define STAGE(t, b) do {                                                        \
        const int _k0 = (t) * 64;                                               \
        char* _dW = dW + (b) * 8192;                                            \
        GLOAD_LDS16(wsrc0 + _k0, _dW);                                          \
        GLOAD_LDS16(wsrc1 + _k0, _dW + 1024);                                   \
        GLOAD_LDS16(wsrc2 + _k0, _dW + 2048);                                   \
        GLOAD_LDS16(wsrc3 + _k0, _dW + 3072);                                   \
        const char* _as = asrc + (size_t)(2 * (t) + w) * 8192;                  \
        char* _dA = dA + (b) * 8192;                                            \
        GLOAD_LDS16(_as,        _dA);                                           \
        GLOAD_LDS16(_as + 1024, _dA + 1024);                                    \
        GLOAD_LDS16(_as + 2048, _dA + 2048);                                    \
        GLOAD_LDS16(_as + 3072, _dA + 3072);                                    \
    } while (0)

    // compute-side read bases (r3 pattern; W buffer stride now 8192)
    const char* rA = lds + (lane << 4);                        // + b*8192 + kbl*4096 + m*1024
    const char* rW = lds + 16384 + (w << 12) + (cl << 8);      // + b*8192 + inner
    const int sw   = (cl & 7) << 4;
    const int q32  = cq << 5;

#define COMPUTE(b) do {                                                         \
        _Pragma("unroll")                                                       \
        for (int _kbl = 0; _kbl < 2; ++_kbl) {                                  \
            int _ib = ((_kbl << 7) + q32) ^ sw;                                 \
            i32x4 _lo = *reinterpret_cast<const i32x4*>(rW + (b) * 8192 + _ib);        \
            i32x4 _hi = *reinterpret_cast<const i32x4*>(rW + (b) * 8192 + (_ib ^ 16)); \
            short8 _bf;                                                         \
            _bf[0] = (short)i2bf(_lo[0]); _bf[1] = (short)i2bf(_lo[1]);         \
            _bf[2] = (short)i2bf(_lo[2]); _bf[3] = (short)i2bf(_lo[3]);         \
            _bf[4] = (short)i2bf(_hi[0]); _bf[5] = (short)i2bf(_hi[1]);         \
            _bf[6] = (short)i2bf(_hi[2]); _bf[7] = (short)i2bf(_hi[3]);         \
            const char* _ab = rA + (b) * 8192 + _kbl * 4096;                    \
            _Pragma("unroll")                                                   \
            for (int _m = 0; _m < 4; ++_m) {                                    \
                short8 _af = *reinterpret_cast<const short8*>(_ab + _m * 1024); \
                acc[_m] = __builtin_amdgcn_mfma_f32_16x16x32_bf16(_af, _bf, acc[_m], 0, 0, 0); \
            }                                                                   \
        }                                                                       \
    } while (0)

    // ---- main loop: 64 chunks of K=64, verified 2-phase template ----
    STAGE(0, 0);
    __syncthreads();
#pragma unroll 1
    for (int t = 0; t < 63; ++t) {
        const int cb = t & 1;
        STAGE(t + 1, cb ^ 1);
        COMPUTE(cb);
        __syncthreads();
    }
    COMPUTE(1);

    // ---- epilogue: scale + bias, direct store (block owns its 32x64 tile) ----
    const int ncol = n0 + (w << 4) + cl;
    const float s  = scales[ncol] * (1.0f / 127.0f);
    const float bv = bias[ncol];
    const int rb = cq << 2;
#pragma unroll
    for (int m = 0; m < 4; ++m) {
#pragma unroll
        for (int r = 0; r < 4; ++r) {
            int mg = (h << 6) + (m << 4) + rb + r;
            out[(size_t)mg * ND + ncol] = acc[m][r] * s + bv;
        }
    }
#undef STAGE
#undef COMPUTE
}

extern "C" void kernel_launch(void* const* d_in, const int* in_sizes, int n_in,
                              void* d_out, int out_size, void* d_ws, size_t ws_size,
                              hipStream_t stream) {
    const float* x      = (const float*)d_in[0];
    const int*   wgt    = (const int*)d_in[1];     // int8 promoted to int32 by harness
    const float* scales = (const float*)d_in[2];
    const float* bias   = (const float*)d_in[3];
    float* out = (float*)d_out;
    ushort* xp = (ushort*)d_ws;                    // 1 MiB bf16 packed x

    pack_x_kernel<<<MD * KD / (8 * 256), 256, 0, stream>>>(x, xp);
    gemm_kernel<<<1024, 128, 0, stream>>>(wgt, xp, scales, bias, out);
}